// Round 1
// 2203.071 us; speedup vs baseline: 1.4543x; 1.4543x over previous
//
#include <hip/hip_runtime.h>
#include <hip/hip_bf16.h>
#include <math.h>

#define BB 2
#define SS 2048
#define TT 2048
#define DD 256
#define HH 8
#define DHH 32
#define FFF 2048
#define VOC 25426

typedef __attribute__((ext_vector_type(8))) short bhalf8;
typedef __attribute__((ext_vector_type(4))) float f32x4;

// ---------------- prep: tgt ids, embedding + 2x + positional enc, pad flags ----------------
__global__ __launch_bounds__(256) void k_prep(const int* __restrict__ tgt_in,
                                              const float* __restrict__ emb,
                                              float* __restrict__ X,
                                              int* __restrict__ pad,
                                              float* __restrict__ out_ids) {
  int r = blockIdx.x;            // 0..B*T-1
  int d = threadIdx.x;           // 0..255
  int b = r / TT, t = r % TT;
  int id = (t == 0) ? VOC : tgt_in[b * (TT - 1) + (t - 1)];
  float div = __expf(-(float)(d & ~1) * 0.03597789207803197f);  // ln(10000)/256
  float ang = (float)t * div;
  float pe = (d & 1) ? cosf(ang) : sinf(ang);
  X[(size_t)r * DD + d] = 2.0f * emb[(size_t)id * DD + d] + pe;
  if (d == 0) {
    pad[r] = (id != 0) ? 1 : 0;
    out_ids[r] = (float)((t == 0) ? 0 : id);
  }
}

// ---------------- zero padded encoder rows ----------------
__global__ __launch_bounds__(256) void k_mask_enc(const int* __restrict__ src,
                                                  const float* __restrict__ enc_in,
                                                  float* __restrict__ enc) {
  int r = blockIdx.x, d = threadIdx.x;
  enc[(size_t)r * DD + d] = (src[r] != 0) ? enc_in[(size_t)r * DD + d] : 0.0f;
}

// ---------------- split-bf16 helpers: x = hi(trunc bf16) + lo(rn bf16), fp32-accurate GEMM via
//                  Ah*Bh + Ah*Bl + Al*Bh on the matrix pipe ----------------
__device__ __forceinline__ void split2(float x0, float x1, unsigned& hp, unsigned& lp) {
  unsigned u0 = __float_as_uint(x0), u1 = __float_as_uint(x1);
  hp = __builtin_amdgcn_perm(u1, u0, 0x07060302u);   // [x0.hi16, x1.hi16] packed
  float l0 = x0 - __uint_as_float(u0 & 0xffff0000u);
  float l1 = x1 - __uint_as_float(u1 & 0xffff0000u);
  __hip_bfloat16 b0 = __float2bfloat16(l0);
  __hip_bfloat16 b1 = __float2bfloat16(l1);
  unsigned short s0 = *reinterpret_cast<unsigned short*>(&b0);
  unsigned short s1 = *reinterpret_cast<unsigned short*>(&b1);
  lp = (unsigned)s0 | ((unsigned)s1 << 16);
}

__device__ __forceinline__ bhalf8 mk8(uint2 a, uint2 b) {
  union { unsigned u[4]; bhalf8 s; } t;
  t.u[0] = a.x; t.u[1] = a.y; t.u[2] = b.x; t.u[3] = b.y;
  return t.s;
}

// ---------------- MFMA GEMM: C = A[M,K] @ B[K,N] (+bias)(+gelu), fp32 in/out ----------------
// 256 threads = 4 waves (2x2). Wave tile = (BM/2)x(BN/2), 16x16x32 bf16 MFMA fragments.
// A and B staged to LDS as separate hi/lo bf16 arrays, layout [row-or-col][k], LDK=40 pad.
template <int BM, int BN>
__global__ __launch_bounds__(256, 2) void k_gemm_mfma(const float* __restrict__ A,
                                                      const float* __restrict__ Bw,
                                                      const float* __restrict__ bias,
                                                      float* __restrict__ C,
                                                      int M, int N, int K, int act) {
  constexpr int BK = 32;
  constexpr int LDK = 40;                 // padded k-dim (bf16 elems); 80B rows -> even bank spread
  constexpr int WM = BM / 2, WN = BN / 2;
  constexpr int FM = WM / 16, FN = WN / 16;
  constexpr int AF4 = BM * BK / 1024;     // float4 per thread for A tile
  constexpr int KPT = BK / (256 / BN);    // k elems per thread for B tile

  __shared__ __align__(16) unsigned short AsH[BM][LDK];
  __shared__ __align__(16) unsigned short AsL[BM][LDK];
  __shared__ __align__(16) unsigned short BsH[BN][LDK];
  __shared__ __align__(16) unsigned short BsL[BN][LDK];

  int tid = threadIdx.x;
  int lane = tid & 63, wid = tid >> 6;
  int wr = wid >> 1, wc = wid & 1;
  int r16 = lane & 15, kg = lane >> 4;
  int bm = blockIdx.y * BM, bn = blockIdx.x * BN;

  int bcol = tid & (BN - 1);
  int bkr0 = (tid / BN) * KPT;
  int colg = bn + bcol;
  bool colok = colg < N;

  float4 aReg[AF4];
  float bReg[KPT];

  auto loadTile = [&](int k0) {
#pragma unroll
    for (int i = 0; i < AF4; ++i) {
      int idx = tid + 256 * i;
      int row = idx >> 3, c4 = idx & 7;   // BK/4 = 8 float4 per row
      aReg[i] = *reinterpret_cast<const float4*>(&A[(size_t)(bm + row) * K + k0 + c4 * 4]);
    }
#pragma unroll
    for (int i = 0; i < KPT; ++i)
      bReg[i] = colok ? Bw[(size_t)(k0 + bkr0 + i) * N + colg] : 0.0f;
  };

  auto stash = [&]() {
#pragma unroll
    for (int i = 0; i < AF4; ++i) {
      int idx = tid + 256 * i;
      int row = idx >> 3, c4 = idx & 7;
      unsigned hp0, lp0, hp1, lp1;
      split2(aReg[i].x, aReg[i].y, hp0, lp0);
      split2(aReg[i].z, aReg[i].w, hp1, lp1);
      *reinterpret_cast<uint2*>(&AsH[row][c4 * 4]) = make_uint2(hp0, hp1);
      *reinterpret_cast<uint2*>(&AsL[row][c4 * 4]) = make_uint2(lp0, lp1);
    }
    unsigned hb[KPT / 2], lb[KPT / 2];
#pragma unroll
    for (int i = 0; i < KPT; i += 2) split2(bReg[i], bReg[i + 1], hb[i / 2], lb[i / 2]);
#pragma unroll
    for (int i = 0; i < KPT / 2; i += 4) {
      *reinterpret_cast<uint4*>(&BsH[bcol][bkr0 + 2 * i]) =
          make_uint4(hb[i], hb[i + 1], hb[i + 2], hb[i + 3]);
      *reinterpret_cast<uint4*>(&BsL[bcol][bkr0 + 2 * i]) =
          make_uint4(lb[i], lb[i + 1], lb[i + 2], lb[i + 3]);
    }
  };

  f32x4 acc[FM][FN];
#pragma unroll
  for (int fi = 0; fi < FM; ++fi)
#pragma unroll
    for (int fj = 0; fj < FN; ++fj) acc[fi][fj] = f32x4{0.0f, 0.0f, 0.0f, 0.0f};

  auto computeTile = [&]() {
    bhalf8 ah[FM], al[FM], bh[FN], bl[FN];
#pragma unroll
    for (int fi = 0; fi < FM; ++fi) {
      const unsigned short* p = &AsH[wr * WM + fi * 16 + r16][kg * 4];
      ah[fi] = mk8(*reinterpret_cast<const uint2*>(p), *reinterpret_cast<const uint2*>(p + 16));
      const unsigned short* q = &AsL[wr * WM + fi * 16 + r16][kg * 4];
      al[fi] = mk8(*reinterpret_cast<const uint2*>(q), *reinterpret_cast<const uint2*>(q + 16));
    }
#pragma unroll
    for (int fj = 0; fj < FN; ++fj) {
      const unsigned short* p = &BsH[wc * WN + fj * 16 + r16][kg * 4];
      bh[fj] = mk8(*reinterpret_cast<const uint2*>(p), *reinterpret_cast<const uint2*>(p + 16));
      const unsigned short* q = &BsL[wc * WN + fj * 16 + r16][kg * 4];
      bl[fj] = mk8(*reinterpret_cast<const uint2*>(q), *reinterpret_cast<const uint2*>(q + 16));
    }
#pragma unroll
    for (int fi = 0; fi < FM; ++fi)
#pragma unroll
      for (int fj = 0; fj < FN; ++fj) {
        acc[fi][fj] = __builtin_amdgcn_mfma_f32_16x16x32_bf16(ah[fi], bh[fj], acc[fi][fj], 0, 0, 0);
        acc[fi][fj] = __builtin_amdgcn_mfma_f32_16x16x32_bf16(ah[fi], bl[fj], acc[fi][fj], 0, 0, 0);
        acc[fi][fj] = __builtin_amdgcn_mfma_f32_16x16x32_bf16(al[fi], bh[fj], acc[fi][fj], 0, 0, 0);
      }
  };

  loadTile(0);
  stash();
  __syncthreads();
  for (int k0 = BK; k0 < K; k0 += BK) {
    loadTile(k0);        // prefetch next tile into regs; overlaps MFMA below
    computeTile();
    __syncthreads();
    stash();
    __syncthreads();
  }
  computeTile();

#pragma unroll
  for (int fj = 0; fj < FN; ++fj) {
    int col = bn + wc * WN + fj * 16 + r16;
    if (col < N) {
      float bs = bias ? bias[col] : 0.0f;
#pragma unroll
      for (int fi = 0; fi < FM; ++fi) {
#pragma unroll
        for (int r = 0; r < 4; ++r) {
          int row = bm + wr * WM + fi * 16 + kg * 4 + r;
          float v = acc[fi][fj][r] + bs;
          if (act == 1) v = 0.5f * v * (1.0f + erff(v * 0.70710678118654752f));
          C[(size_t)row * N + col] = v;
        }
      }
    }
  }
}

// ---------------- flash-style attention: 64 queries per block, 4 threads/query ----------------
__global__ __launch_bounds__(256) void k_flash(const float* __restrict__ Qb,
                                               const float* __restrict__ Kb,
                                               const float* __restrict__ Vb,
                                               float* __restrict__ Ob,
                                               const int* __restrict__ pad,
                                               int Tq, int Tk, int causal) {
  __shared__ float Kt[64][DHH];
  __shared__ float Vt[64][DHH];
  int t = threadIdx.x;
  int qi = t >> 2, sub = t & 3;          // 64 queries x 4 dim-groups of 8
  int qt = blockIdx.x, bh = blockIdx.y;
  int b = bh / HH, h = bh % HH;
  int qg = qt * 64 + qi;
  float qv[8], ov[8];
  const float* qrow = Qb + ((size_t)(b * Tq + qg)) * DD + h * DHH + sub * 8;
#pragma unroll
  for (int j = 0; j < 8; j++) { qv[j] = qrow[j]; ov[j] = 0.0f; }
  float m = -3.0e38f, l = 0.0f;
  int ntiles = causal ? (qt + 1) : (Tk / 64);
  for (int kt = 0; kt < ntiles; kt++) {
    int kb = kt * 64;
#pragma unroll
    for (int i = 0; i < 8; i++) {
      int lidx = t + 256 * i;             // 0..2047
      int rr = lidx >> 5, cc = lidx & 31;
      Kt[rr][cc] = Kb[((size_t)(b * Tk + kb + rr)) * DD + h * DHH + cc];
      Vt[rr][cc] = Vb[((size_t)(b * Tk + kb + rr)) * DD + h * DHH + cc];
    }
    __syncthreads();
    for (int j = 0; j < 64; j++) {
      int kg2 = kb + j;
      bool valid = true;
      if (causal) valid = (kg2 <= qg) && (pad[b * Tq + kg2] != 0);
      if (valid) {
        float part = 0.0f;
#pragma unroll
        for (int jj = 0; jj < 8; jj++) part += qv[jj] * Kt[j][sub * 8 + jj];
        part += __shfl_xor(part, 1, 4);
        part += __shfl_xor(part, 2, 4);
        float s = part * 0.17677669529663687f;  // 1/sqrt(32)
        float mn = fmaxf(m, s);
        float corr = __expf(m - mn);
        float p = __expf(s - mn);
        l = l * corr + p;
#pragma unroll
        for (int jj = 0; jj < 8; jj++) ov[jj] = ov[jj] * corr + p * Vt[j][sub * 8 + jj];
        m = mn;
      }
    }
    __syncthreads();
  }
  float inv = 1.0f / l;
  float* orow = Ob + ((size_t)(b * Tq + qg)) * DD + h * DHH + sub * 8;
#pragma unroll
  for (int j = 0; j < 8; j++) orow[j] = ov[j] * inv;
}

// ---------------- fused residual add + LayerNorm (row-per-block, D=256) ----------------
__global__ __launch_bounds__(256) void k_add_ln(const float* __restrict__ xin,
                                                const float* __restrict__ delta,
                                                const float* __restrict__ g,
                                                const float* __restrict__ be,
                                                float* __restrict__ out) {
  __shared__ float sb[256];
  int r = blockIdx.x, d = threadIdx.x;
  float v = xin[(size_t)r * DD + d] + delta[(size_t)r * DD + d];
  sb[d] = v;
  __syncthreads();
  for (int s = 128; s > 0; s >>= 1) { if (d < s) sb[d] += sb[d + s]; __syncthreads(); }
  float mean = sb[0] * (1.0f / DD);
  __syncthreads();
  float c = v - mean;
  sb[d] = c * c;
  __syncthreads();
  for (int s = 128; s > 0; s >>= 1) { if (d < s) sb[d] += sb[d + s]; __syncthreads(); }
  float var = sb[0] * (1.0f / DD);
  out[(size_t)r * DD + d] = c * rsqrtf(var + 1e-5f) * g[d] + be[d];
}

extern "C" void kernel_launch(void* const* d_in, const int* in_sizes, int n_in,
                              void* d_out, int out_size, void* d_ws, size_t ws_size,
                              hipStream_t stream) {
  const int*   src    = (const int*)  d_in[0];
  const int*   tgt    = (const int*)  d_in[1];
  const float* enc_in = (const float*)d_in[2];
  const float* emb    = (const float*)d_in[3];
  const float* Wq_s   = (const float*)d_in[4];
  const float* Wk_s   = (const float*)d_in[5];
  const float* Wv_s   = (const float*)d_in[6];
  const float* Wo_s   = (const float*)d_in[7];
  const float* bo_s   = (const float*)d_in[8];
  const float* Wq_c   = (const float*)d_in[9];
  const float* Wk_c   = (const float*)d_in[10];
  const float* Wv_c   = (const float*)d_in[11];
  const float* Wo_c   = (const float*)d_in[12];
  const float* bo_c   = (const float*)d_in[13];
  const float* W1     = (const float*)d_in[14];
  const float* b1     = (const float*)d_in[15];
  const float* W2     = (const float*)d_in[16];
  const float* b2     = (const float*)d_in[17];
  const float* g1     = (const float*)d_in[18];
  const float* be1    = (const float*)d_in[19];
  const float* g2     = (const float*)d_in[20];
  const float* be2    = (const float*)d_in[21];
  const float* g3     = (const float*)d_in[22];
  const float* be3    = (const float*)d_in[23];
  const float* Wf     = (const float*)d_in[24];
  const float* bf     = (const float*)d_in[25];

  float* logits  = (float*)d_out;
  float* out_ids = logits + (size_t)BB * TT * VOC;   // last B*T floats of d_out

  const size_t NTD = (size_t)BB * TT * DD;  // 1,048,576 floats (4 MB)

  // X must survive the final vocab GEMM (which overwrites the logits region),
  // so it is the ONLY large buffer kept in d_ws (4 MB).
  float* X = (float*)d_ws;

  // All other intermediates are dead before the vocab GEMM runs; stage them
  // inside the (417 MB) logits region.
  float* Qb  = logits;
  float* Kb  = Qb  + NTD;
  float* Vb  = Kb  + NTD;
  float* XA  = Vb  + NTD;
  float* ENC = XA  + NTD;
  float* HID = ENC + NTD;                    // B*T*FF = 8,388,608 floats (32 MB)
  float* P   = HID;                          // alias: proj temp (HID dead until FFN)
  int*   PAD = (int*)(HID + (size_t)BB * TT * FFF);

  dim3 blk(256);
  const int M = BB * TT;  // 4096

  // 1) embed + PE + tgt-ids output + pad flags; masked encoder
  k_prep<<<dim3(BB * TT), blk, 0, stream>>>(tgt, emb, X, PAD, out_ids);
  k_mask_enc<<<dim3(BB * SS), blk, 0, stream>>>(src, enc_in, ENC);

  // 2) self-attention (all GEMMs on matrix pipe via split-bf16 3-term MFMA)
  k_gemm_mfma<64, 64><<<dim3(DD / 64, M / 64), blk, 0, stream>>>(X, Wq_s, nullptr, Qb, M, DD, DD, 0);
  k_gemm_mfma<64, 64><<<dim3(DD / 64, M / 64), blk, 0, stream>>>(X, Wk_s, nullptr, Kb, M, DD, DD, 0);
  k_gemm_mfma<64, 64><<<dim3(DD / 64, M / 64), blk, 0, stream>>>(X, Wv_s, nullptr, Vb, M, DD, DD, 0);
  k_flash<<<dim3(TT / 64, BB * HH), blk, 0, stream>>>(Qb, Kb, Vb, XA, PAD, TT, TT, 1);
  k_gemm_mfma<64, 64><<<dim3(DD / 64, M / 64), blk, 0, stream>>>(XA, Wo_s, bo_s, P, M, DD, DD, 0);
  k_add_ln<<<dim3(M), blk, 0, stream>>>(X, P, g1, be1, X);

  // 3) cross-attention (keys/values from masked encoder; scores unmasked)
  k_gemm_mfma<64, 64><<<dim3(DD / 64, M / 64), blk, 0, stream>>>(X, Wq_c, nullptr, Qb, M, DD, DD, 0);
  k_gemm_mfma<64, 64><<<dim3(DD / 64, M / 64), blk, 0, stream>>>(ENC, Wk_c, nullptr, Kb, BB * SS, DD, DD, 0);
  k_gemm_mfma<64, 64><<<dim3(DD / 64, M / 64), blk, 0, stream>>>(ENC, Wv_c, nullptr, Vb, BB * SS, DD, DD, 0);
  k_flash<<<dim3(TT / 64, BB * HH), blk, 0, stream>>>(Qb, Kb, Vb, XA, nullptr, TT, SS, 0);
  k_gemm_mfma<64, 64><<<dim3(DD / 64, M / 64), blk, 0, stream>>>(XA, Wo_c, bo_c, P, M, DD, DD, 0);
  k_add_ln<<<dim3(M), blk, 0, stream>>>(X, P, g2, be2, X);

  // 4) FFN (exact GELU fused into first GEMM)
  k_gemm_mfma<128, 128><<<dim3(FFF / 128, M / 128), blk, 0, stream>>>(X, W1, b1, HID, M, FFF, DD, 1);
  k_gemm_mfma<64, 64><<<dim3(DD / 64, M / 64), blk, 0, stream>>>(HID, W2, b2, XA, M, DD, FFF, 0);
  k_add_ln<<<dim3(M), blk, 0, stream>>>(X, XA, g3, be3, X);

  // 5) vocab projection -> logits (dominant dispatch; overwrites scratch region)
  k_gemm_mfma<128, 128><<<dim3((VOC + 127) / 128, M / 128), blk, 0, stream>>>(X, Wf, bf, logits, M, VOC, DD, 0);
}

// Round 2
// 1158.540 us; speedup vs baseline: 2.7655x; 1.9016x over previous
//
#include <hip/hip_runtime.h>
#include <hip/hip_bf16.h>
#include <math.h>

#define BB 2
#define SS 2048
#define TT 2048
#define DD 256
#define HH 8
#define DHH 32
#define FFF 2048
#define VOC 25426

typedef __attribute__((ext_vector_type(8))) short bhalf8;
typedef __attribute__((ext_vector_type(4))) float f32x4;

// ---------------- prep: tgt ids, embedding + 2x + positional enc, pad flags ----------------
__global__ __launch_bounds__(256) void k_prep(const int* __restrict__ tgt_in,
                                              const float* __restrict__ emb,
                                              float* __restrict__ X,
                                              int* __restrict__ pad,
                                              float* __restrict__ out_ids) {
  int r = blockIdx.x;            // 0..B*T-1
  int d = threadIdx.x;           // 0..255
  int b = r / TT, t = r % TT;
  int id = (t == 0) ? VOC : tgt_in[b * (TT - 1) + (t - 1)];
  float div = __expf(-(float)(d & ~1) * 0.03597789207803197f);  // ln(10000)/256
  float ang = (float)t * div;
  float pe = (d & 1) ? cosf(ang) : sinf(ang);
  X[(size_t)r * DD + d] = 2.0f * emb[(size_t)id * DD + d] + pe;
  if (d == 0) {
    pad[r] = (id != 0) ? 1 : 0;
    out_ids[r] = (float)((t == 0) ? 0 : id);
  }
}

// ---------------- zero padded encoder rows ----------------
__global__ __launch_bounds__(256) void k_mask_enc(const int* __restrict__ src,
                                                  const float* __restrict__ enc_in,
                                                  float* __restrict__ enc) {
  int r = blockIdx.x, d = threadIdx.x;
  enc[(size_t)r * DD + d] = (src[r] != 0) ? enc_in[(size_t)r * DD + d] : 0.0f;
}

// ---------------- split-bf16 helpers ----------------
__device__ __forceinline__ void split2(float x0, float x1, unsigned& hp, unsigned& lp) {
  unsigned u0 = __float_as_uint(x0), u1 = __float_as_uint(x1);
  hp = __builtin_amdgcn_perm(u1, u0, 0x07060302u);   // [x0.hi16, x1.hi16] packed
  float l0 = x0 - __uint_as_float(u0 & 0xffff0000u);
  float l1 = x1 - __uint_as_float(u1 & 0xffff0000u);
  __hip_bfloat16 b0 = __float2bfloat16(l0);
  __hip_bfloat16 b1 = __float2bfloat16(l1);
  unsigned short s0 = *reinterpret_cast<unsigned short*>(&b0);
  unsigned short s1 = *reinterpret_cast<unsigned short*>(&b1);
  lp = (unsigned)s0 | ((unsigned)s1 << 16);
}

__device__ __forceinline__ bhalf8 mk8(uint2 a, uint2 b) {
  union { unsigned u[4]; bhalf8 s; } t;
  t.u[0] = a.x; t.u[1] = a.y; t.u[2] = b.x; t.u[3] = b.y;
  return t.s;
}

// ---------------- MFMA GEMM: C = A[M,K] @ B[K,N] (+bias)(+gelu), fp32 in/out ----------------
template <int BM, int BN>
__global__ __launch_bounds__(256, 2) void k_gemm_mfma(const float* __restrict__ A,
                                                      const float* __restrict__ Bw,
                                                      const float* __restrict__ bias,
                                                      float* __restrict__ C,
                                                      int M, int N, int K, int act) {
  constexpr int BK = 32;
  constexpr int LDK = 40;
  constexpr int WM = BM / 2, WN = BN / 2;
  constexpr int FM = WM / 16, FN = WN / 16;
  constexpr int AF4 = BM * BK / 1024;
  constexpr int KPT = BK / (256 / BN);

  __shared__ __align__(16) unsigned short AsH[BM][LDK];
  __shared__ __align__(16) unsigned short AsL[BM][LDK];
  __shared__ __align__(16) unsigned short BsH[BN][LDK];
  __shared__ __align__(16) unsigned short BsL[BN][LDK];

  int tid = threadIdx.x;
  int lane = tid & 63, wid = tid >> 6;
  int wr = wid >> 1, wc = wid & 1;
  int r16 = lane & 15, kg = lane >> 4;
  int bm = blockIdx.y * BM, bn = blockIdx.x * BN;

  int bcol = tid & (BN - 1);
  int bkr0 = (tid / BN) * KPT;
  int colg = bn + bcol;
  bool colok = colg < N;

  float4 aReg[AF4];
  float bReg[KPT];

  auto loadTile = [&](int k0) {
#pragma unroll
    for (int i = 0; i < AF4; ++i) {
      int idx = tid + 256 * i;
      int row = idx >> 3, c4 = idx & 7;
      aReg[i] = *reinterpret_cast<const float4*>(&A[(size_t)(bm + row) * K + k0 + c4 * 4]);
    }
#pragma unroll
    for (int i = 0; i < KPT; ++i)
      bReg[i] = colok ? Bw[(size_t)(k0 + bkr0 + i) * N + colg] : 0.0f;
  };

  auto stash = [&]() {
#pragma unroll
    for (int i = 0; i < AF4; ++i) {
      int idx = tid + 256 * i;
      int row = idx >> 3, c4 = idx & 7;
      unsigned hp0, lp0, hp1, lp1;
      split2(aReg[i].x, aReg[i].y, hp0, lp0);
      split2(aReg[i].z, aReg[i].w, hp1, lp1);
      *reinterpret_cast<uint2*>(&AsH[row][c4 * 4]) = make_uint2(hp0, hp1);
      *reinterpret_cast<uint2*>(&AsL[row][c4 * 4]) = make_uint2(lp0, lp1);
    }
    unsigned hb[KPT / 2], lb[KPT / 2];
#pragma unroll
    for (int i = 0; i < KPT; i += 2) split2(bReg[i], bReg[i + 1], hb[i / 2], lb[i / 2]);
#pragma unroll
    for (int i = 0; i < KPT / 2; i += 4) {
      *reinterpret_cast<uint4*>(&BsH[bcol][bkr0 + 2 * i]) =
          make_uint4(hb[i], hb[i + 1], hb[i + 2], hb[i + 3]);
      *reinterpret_cast<uint4*>(&BsL[bcol][bkr0 + 2 * i]) =
          make_uint4(lb[i], lb[i + 1], lb[i + 2], lb[i + 3]);
    }
  };

  f32x4 acc[FM][FN];
#pragma unroll
  for (int fi = 0; fi < FM; ++fi)
#pragma unroll
    for (int fj = 0; fj < FN; ++fj) acc[fi][fj] = f32x4{0.0f, 0.0f, 0.0f, 0.0f};

  auto computeTile = [&]() {
    bhalf8 ah[FM], al[FM], bh[FN], bl[FN];
#pragma unroll
    for (int fi = 0; fi < FM; ++fi) {
      const unsigned short* p = &AsH[wr * WM + fi * 16 + r16][kg * 4];
      ah[fi] = mk8(*reinterpret_cast<const uint2*>(p), *reinterpret_cast<const uint2*>(p + 16));
      const unsigned short* q = &AsL[wr * WM + fi * 16 + r16][kg * 4];
      al[fi] = mk8(*reinterpret_cast<const uint2*>(q), *reinterpret_cast<const uint2*>(q + 16));
    }
#pragma unroll
    for (int fj = 0; fj < FN; ++fj) {
      const unsigned short* p = &BsH[wc * WN + fj * 16 + r16][kg * 4];
      bh[fj] = mk8(*reinterpret_cast<const uint2*>(p), *reinterpret_cast<const uint2*>(p + 16));
      const unsigned short* q = &BsL[wc * WN + fj * 16 + r16][kg * 4];
      bl[fj] = mk8(*reinterpret_cast<const uint2*>(q), *reinterpret_cast<const uint2*>(q + 16));
    }
#pragma unroll
    for (int fi = 0; fi < FM; ++fi)
#pragma unroll
      for (int fj = 0; fj < FN; ++fj) {
        acc[fi][fj] = __builtin_amdgcn_mfma_f32_16x16x32_bf16(ah[fi], bh[fj], acc[fi][fj], 0, 0, 0);
        acc[fi][fj] = __builtin_amdgcn_mfma_f32_16x16x32_bf16(ah[fi], bl[fj], acc[fi][fj], 0, 0, 0);
        acc[fi][fj] = __builtin_amdgcn_mfma_f32_16x16x32_bf16(al[fi], bh[fj], acc[fi][fj], 0, 0, 0);
      }
  };

  loadTile(0);
  stash();
  __syncthreads();
  for (int k0 = BK; k0 < K; k0 += BK) {
    loadTile(k0);
    computeTile();
    __syncthreads();
    stash();
    __syncthreads();
  }
  computeTile();

#pragma unroll
  for (int fj = 0; fj < FN; ++fj) {
    int col = bn + wc * WN + fj * 16 + r16;
    if (col < N) {
      float bs = bias ? bias[col] : 0.0f;
#pragma unroll
      for (int fi = 0; fi < FM; ++fi) {
#pragma unroll
        for (int r = 0; r < 4; ++r) {
          int row = bm + wr * WM + fi * 16 + kg * 4 + r;
          float v = acc[fi][fj][r] + bs;
          if (act == 1) v = 0.5f * v * (1.0f + erff(v * 0.70710678118654752f));
          C[(size_t)row * N + col] = v;
        }
      }
    }
  }
}

// ---------------- MFMA flash attention (swapped: S^T = K·Q^T, O^T = V^T·P^T) ----------------
// 256 threads = 4 waves; each wave owns 16 queries; block owns 64 queries of one (b,h).
// Split-bf16 3-term on both QK^T and PV for fp32-level accuracy.
// P^T lives entirely in registers: S^T C-layout == PV B-fragment layout.
__global__ __launch_bounds__(256) void k_flash_mfma(const float* __restrict__ Qb,
                                                    const float* __restrict__ Kb,
                                                    const float* __restrict__ Vb,
                                                    float* __restrict__ Ob,
                                                    const int* __restrict__ pad,
                                                    int Tq, int Tk, int causal) {
  constexpr int LDK = 40;
  __shared__ __align__(16) unsigned short KsH[32][LDK];
  __shared__ __align__(16) unsigned short KsL[32][LDK];
  __shared__ __align__(16) unsigned short VtH[32][LDK];
  __shared__ __align__(16) unsigned short VtL[32][LDK];
  __shared__ int padS[32];

  int tid = threadIdx.x;
  int lane = tid & 63, wid = tid >> 6;
  int r16 = lane & 15, kg = lane >> 4;
  int qt = blockIdx.x, bh = blockIdx.y;
  int b = bh / HH, h = bh % HH;
  int qg = qt * 64 + wid * 16 + r16;     // this lane's query (= C column)

  // Q fragment: pre-scaled by 1/sqrt(dh), split into hi/lo bf16
  const float* qrow = Qb + (size_t)(b * Tq + qg) * DD + h * DHH;
  float4 q0 = *reinterpret_cast<const float4*>(qrow + kg * 4);
  float4 q1 = *reinterpret_cast<const float4*>(qrow + kg * 4 + 16);
  const float sc = 0.17677669529663687f;  // 1/sqrt(32)
  unsigned qh0, ql0, qh1, ql1, qh2, ql2, qh3, ql3;
  split2(q0.x * sc, q0.y * sc, qh0, ql0);
  split2(q0.z * sc, q0.w * sc, qh1, ql1);
  split2(q1.x * sc, q1.y * sc, qh2, ql2);
  split2(q1.z * sc, q1.w * sc, qh3, ql3);
  bhalf8 qh = mk8(make_uint2(qh0, qh1), make_uint2(qh2, qh3));
  bhalf8 ql = mk8(make_uint2(ql0, ql1), make_uint2(ql2, ql3));

  f32x4 accO[2];
  accO[0] = f32x4{0.0f, 0.0f, 0.0f, 0.0f};
  accO[1] = f32x4{0.0f, 0.0f, 0.0f, 0.0f};
  float m = -3.0e38f, l = 0.0f;

  // staging indices: coalesced K/V row reads
  int skey = tid >> 3, sd0 = (tid & 7) * 4;

  int ntiles = causal ? (qt * 2 + 2) : (Tk / 32);
  for (int kt = 0; kt < ntiles; ++kt) {
    int kb = kt * 32;
    __syncthreads();
    {
      const float* kr = Kb + (size_t)(b * Tk + kb + skey) * DD + h * DHH + sd0;
      float4 kv = *reinterpret_cast<const float4*>(kr);
      unsigned hA, lA, hB, lB;
      split2(kv.x, kv.y, hA, lA);
      split2(kv.z, kv.w, hB, lB);
      *reinterpret_cast<uint2*>(&KsH[skey][sd0]) = make_uint2(hA, hB);
      *reinterpret_cast<uint2*>(&KsL[skey][sd0]) = make_uint2(lA, lB);
      const float* vr = Vb + (size_t)(b * Tk + kb + skey) * DD + h * DHH + sd0;
      float4 vv = *reinterpret_cast<const float4*>(vr);
      split2(vv.x, vv.y, hA, lA);
      split2(vv.z, vv.w, hB, lB);
      VtH[sd0 + 0][skey] = (unsigned short)(hA & 0xffff);
      VtH[sd0 + 1][skey] = (unsigned short)(hA >> 16);
      VtH[sd0 + 2][skey] = (unsigned short)(hB & 0xffff);
      VtH[sd0 + 3][skey] = (unsigned short)(hB >> 16);
      VtL[sd0 + 0][skey] = (unsigned short)(lA & 0xffff);
      VtL[sd0 + 1][skey] = (unsigned short)(lA >> 16);
      VtL[sd0 + 2][skey] = (unsigned short)(lB & 0xffff);
      VtL[sd0 + 3][skey] = (unsigned short)(lB >> 16);
      if (causal && tid < 32) padS[tid] = pad[(size_t)b * Tq + kb + tid];
    }
    __syncthreads();

    // S^T = K·Q^T : two 16-key subtiles, 3-term split
    f32x4 s0 = f32x4{0.0f, 0.0f, 0.0f, 0.0f};
    f32x4 s1 = f32x4{0.0f, 0.0f, 0.0f, 0.0f};
    {
      const unsigned short* p0 = &KsH[r16][kg * 4];
      const unsigned short* q0p = &KsL[r16][kg * 4];
      bhalf8 kh0 = mk8(*reinterpret_cast<const uint2*>(p0), *reinterpret_cast<const uint2*>(p0 + 16));
      bhalf8 kl0 = mk8(*reinterpret_cast<const uint2*>(q0p), *reinterpret_cast<const uint2*>(q0p + 16));
      const unsigned short* p1 = &KsH[16 + r16][kg * 4];
      const unsigned short* q1p = &KsL[16 + r16][kg * 4];
      bhalf8 kh1 = mk8(*reinterpret_cast<const uint2*>(p1), *reinterpret_cast<const uint2*>(p1 + 16));
      bhalf8 kl1 = mk8(*reinterpret_cast<const uint2*>(q1p), *reinterpret_cast<const uint2*>(q1p + 16));
      s0 = __builtin_amdgcn_mfma_f32_16x16x32_bf16(kh0, qh, s0, 0, 0, 0);
      s0 = __builtin_amdgcn_mfma_f32_16x16x32_bf16(kh0, ql, s0, 0, 0, 0);
      s0 = __builtin_amdgcn_mfma_f32_16x16x32_bf16(kl0, qh, s0, 0, 0, 0);
      s1 = __builtin_amdgcn_mfma_f32_16x16x32_bf16(kh1, qh, s1, 0, 0, 0);
      s1 = __builtin_amdgcn_mfma_f32_16x16x32_bf16(kh1, ql, s1, 0, 0, 0);
      s1 = __builtin_amdgcn_mfma_f32_16x16x32_bf16(kl1, qh, s1, 0, 0, 0);
    }

    // lane-resident scores: key j<4 -> kb+kg*4+j ; j>=4 -> kb+16+kg*4+(j-4)
    float sv[8];
#pragma unroll
    for (int j = 0; j < 4; ++j) { sv[j] = s0[j]; sv[4 + j] = s1[j]; }
    if (causal) {
#pragma unroll
      for (int j = 0; j < 8; ++j) {
        int kk = (j < 4) ? (kg * 4 + j) : (16 + kg * 4 + (j - 4));
        bool ok = (kb + kk <= qg) && (padS[kk] != 0);
        sv[j] = ok ? sv[j] : -3.0e38f;
      }
    }

    // online softmax (per query = per lane after cross-kg reduce)
    float mt = fmaxf(fmaxf(fmaxf(sv[0], sv[1]), fmaxf(sv[2], sv[3])),
                     fmaxf(fmaxf(sv[4], sv[5]), fmaxf(sv[6], sv[7])));
    mt = fmaxf(mt, __shfl_xor(mt, 16));
    mt = fmaxf(mt, __shfl_xor(mt, 32));
    float mn = fmaxf(m, mt);
    float corr = __expf(m - mn);
    float p[8];
#pragma unroll
    for (int j = 0; j < 8; ++j) p[j] = __expf(sv[j] - mn);
    float ts = ((p[0] + p[1]) + (p[2] + p[3])) + ((p[4] + p[5]) + (p[6] + p[7]));
    ts += __shfl_xor(ts, 16);
    ts += __shfl_xor(ts, 32);
    l = l * corr + ts;
    m = mn;

    // pack P^T into PV B-fragments (hi/lo)
    unsigned ph0, pl0, ph1, pl1, ph2, pl2, ph3, pl3;
    split2(p[0], p[1], ph0, pl0);
    split2(p[2], p[3], ph1, pl1);
    split2(p[4], p[5], ph2, pl2);
    split2(p[6], p[7], ph3, pl3);
    bhalf8 pb = mk8(make_uint2(ph0, ph1), make_uint2(ph2, ph3));
    bhalf8 pl = mk8(make_uint2(pl0, pl1), make_uint2(pl2, pl3));

    // rescale O accumulators, then O^T += V^T · P^T (3-term)
#pragma unroll
    for (int db = 0; db < 2; ++db) {
#pragma unroll
      for (int r = 0; r < 4; ++r) accO[db][r] *= corr;
      const unsigned short* vp = &VtH[db * 16 + r16][kg * 4];
      const unsigned short* vq = &VtL[db * 16 + r16][kg * 4];
      bhalf8 vh = mk8(*reinterpret_cast<const uint2*>(vp), *reinterpret_cast<const uint2*>(vp + 16));
      bhalf8 vl = mk8(*reinterpret_cast<const uint2*>(vq), *reinterpret_cast<const uint2*>(vq + 16));
      accO[db] = __builtin_amdgcn_mfma_f32_16x16x32_bf16(vh, pb, accO[db], 0, 0, 0);
      accO[db] = __builtin_amdgcn_mfma_f32_16x16x32_bf16(vh, pl, accO[db], 0, 0, 0);
      accO[db] = __builtin_amdgcn_mfma_f32_16x16x32_bf16(vl, pb, accO[db], 0, 0, 0);
    }
  }

  float inv = 1.0f / l;
  float* orow = Ob + (size_t)(b * Tq + qg) * DD + h * DHH;
#pragma unroll
  for (int db = 0; db < 2; ++db) {
    f32x4 o = accO[db];
#pragma unroll
    for (int r = 0; r < 4; ++r) o[r] *= inv;
    *reinterpret_cast<float4*>(orow + db * 16 + kg * 4) = *reinterpret_cast<float4*>(&o);
  }
}

// ---------------- fused residual add + LayerNorm (row-per-block, D=256) ----------------
__global__ __launch_bounds__(256) void k_add_ln(const float* __restrict__ xin,
                                                const float* __restrict__ delta,
                                                const float* __restrict__ g,
                                                const float* __restrict__ be,
                                                float* __restrict__ out) {
  __shared__ float sb[256];
  int r = blockIdx.x, d = threadIdx.x;
  float v = xin[(size_t)r * DD + d] + delta[(size_t)r * DD + d];
  sb[d] = v;
  __syncthreads();
  for (int s = 128; s > 0; s >>= 1) { if (d < s) sb[d] += sb[d + s]; __syncthreads(); }
  float mean = sb[0] * (1.0f / DD);
  __syncthreads();
  float c = v - mean;
  sb[d] = c * c;
  __syncthreads();
  for (int s = 128; s > 0; s >>= 1) { if (d < s) sb[d] += sb[d + s]; __syncthreads(); }
  float var = sb[0] * (1.0f / DD);
  out[(size_t)r * DD + d] = c * rsqrtf(var + 1e-5f) * g[d] + be[d];
}

extern "C" void kernel_launch(void* const* d_in, const int* in_sizes, int n_in,
                              void* d_out, int out_size, void* d_ws, size_t ws_size,
                              hipStream_t stream) {
  const int*   src    = (const int*)  d_in[0];
  const int*   tgt    = (const int*)  d_in[1];
  const float* enc_in = (const float*)d_in[2];
  const float* emb    = (const float*)d_in[3];
  const float* Wq_s   = (const float*)d_in[4];
  const float* Wk_s   = (const float*)d_in[5];
  const float* Wv_s   = (const float*)d_in[6];
  const float* Wo_s   = (const float*)d_in[7];
  const float* bo_s   = (const float*)d_in[8];
  const float* Wq_c   = (const float*)d_in[9];
  const float* Wk_c   = (const float*)d_in[10];
  const float* Wv_c   = (const float*)d_in[11];
  const float* Wo_c   = (const float*)d_in[12];
  const float* bo_c   = (const float*)d_in[13];
  const float* W1     = (const float*)d_in[14];
  const float* b1     = (const float*)d_in[15];
  const float* W2     = (const float*)d_in[16];
  const float* b2     = (const float*)d_in[17];
  const float* g1     = (const float*)d_in[18];
  const float* be1    = (const float*)d_in[19];
  const float* g2     = (const float*)d_in[20];
  const float* be2    = (const float*)d_in[21];
  const float* g3     = (const float*)d_in[22];
  const float* be3    = (const float*)d_in[23];
  const float* Wf     = (const float*)d_in[24];
  const float* bf     = (const float*)d_in[25];

  float* logits  = (float*)d_out;
  float* out_ids = logits + (size_t)BB * TT * VOC;   // last B*T floats of d_out

  const size_t NTD = (size_t)BB * TT * DD;  // 1,048,576 floats (4 MB)

  // X must survive the final vocab GEMM; it is the only large buffer in d_ws.
  float* X = (float*)d_ws;

  // All other intermediates are dead before the vocab GEMM; stage in logits region.
  float* Qb  = logits;
  float* Kb  = Qb  + NTD;
  float* Vb  = Kb  + NTD;
  float* XA  = Vb  + NTD;
  float* ENC = XA  + NTD;
  float* HID = ENC + NTD;                    // B*T*FF = 8,388,608 floats (32 MB)
  float* P   = HID;                          // alias: proj temp (HID dead until FFN)
  int*   PAD = (int*)(HID + (size_t)BB * TT * FFF);

  dim3 blk(256);
  const int M = BB * TT;  // 4096

  // 1) embed + PE + tgt-ids output + pad flags; masked encoder
  k_prep<<<dim3(BB * TT), blk, 0, stream>>>(tgt, emb, X, PAD, out_ids);
  k_mask_enc<<<dim3(BB * SS), blk, 0, stream>>>(src, enc_in, ENC);

  // 2) self-attention
  k_gemm_mfma<64, 64><<<dim3(DD / 64, M / 64), blk, 0, stream>>>(X, Wq_s, nullptr, Qb, M, DD, DD, 0);
  k_gemm_mfma<64, 64><<<dim3(DD / 64, M / 64), blk, 0, stream>>>(X, Wk_s, nullptr, Kb, M, DD, DD, 0);
  k_gemm_mfma<64, 64><<<dim3(DD / 64, M / 64), blk, 0, stream>>>(X, Wv_s, nullptr, Vb, M, DD, DD, 0);
  k_flash_mfma<<<dim3(TT / 64, BB * HH), blk, 0, stream>>>(Qb, Kb, Vb, XA, PAD, TT, TT, 1);
  k_gemm_mfma<64, 64><<<dim3(DD / 64, M / 64), blk, 0, stream>>>(XA, Wo_s, bo_s, P, M, DD, DD, 0);
  k_add_ln<<<dim3(M), blk, 0, stream>>>(X, P, g1, be1, X);

  // 3) cross-attention (keys/values from masked encoder; scores unmasked)
  k_gemm_mfma<64, 64><<<dim3(DD / 64, M / 64), blk, 0, stream>>>(X, Wq_c, nullptr, Qb, M, DD, DD, 0);
  k_gemm_mfma<64, 64><<<dim3(DD / 64, M / 64), blk, 0, stream>>>(ENC, Wk_c, nullptr, Kb, BB * SS, DD, DD, 0);
  k_gemm_mfma<64, 64><<<dim3(DD / 64, M / 64), blk, 0, stream>>>(ENC, Wv_c, nullptr, Vb, BB * SS, DD, DD, 0);
  k_flash_mfma<<<dim3(TT / 64, BB * HH), blk, 0, stream>>>(Qb, Kb, Vb, XA, nullptr, TT, SS, 0);
  k_gemm_mfma<64, 64><<<dim3(DD / 64, M / 64), blk, 0, stream>>>(XA, Wo_c, bo_c, P, M, DD, DD, 0);
  k_add_ln<<<dim3(M), blk, 0, stream>>>(X, P, g2, be2, X);

  // 4) FFN (exact GELU fused into first GEMM)
  k_gemm_mfma<128, 128><<<dim3(FFF / 128, M / 128), blk, 0, stream>>>(X, W1, b1, HID, M, FFF, DD, 1);
  k_gemm_mfma<64, 64><<<dim3(DD / 64, M / 64), blk, 0, stream>>>(HID, W2, b2, XA, M, DD, FFF, 0);
  k_add_ln<<<dim3(M), blk, 0, stream>>>(X, XA, g3, be3, X);

  // 5) vocab projection -> logits (dominant dispatch; overwrites scratch region)
  k_gemm_mfma<128, 128><<<dim3((VOC + 127) / 128, M / 128), blk, 0, stream>>>(X, Wf, bf, logits, M, VOC, DD, 0);
}